// Round 19
// baseline (14211.798 us; speedup 1.0000x reference)
//
#include <hip/hip_runtime.h>
#include <math.h>

// NDDE forward-Euler DDE solve, D=768, N=8192 steps.
// x_{j+1} = x_j + dt * tanh(Wx x_j + Wy x_{j-10} + b),  dt = tau/10.
// Output: trajectory [D][N+1] fp32, out[i*(N+1)+k] = x_k[i].
//
// NUMERICS ARE FROZEN (passes at absmax 16.0 / thr 16.4): fp64-exact dots
// rounded per-dot to fp32; fp32 adds for z; correctly-rounded fp32 tanh via
// fp64; fp32 state update mul-then-add; per-row 32-lane x 24-col ownership,
// FMA order and shuffle reduction tree IDENTICAL to rounds 5/11/13.
//
// Round 19 = r18 (13.79 ms) with the first-sweep alignment knob bracketed:
// s_sleep 5 (~320cy) -> s_sleep 8 (~512cy). r18 confirmed the miss-the-bus
// model (sleep 320 bought 460us and cut FETCH 223->206MB = fewer failed
// sweeps); the response curve says we were still under-sleeping. Each
// remaining early-sample miss costs a full ~800cy retry period; extra sleep
// costs its own cycles only. Win -> knee is higher, probe 10 next; lose ->
// knee was ~5, revert and conclude protocol latency floor.
//
// Encoded lessons: no fences (r3), no RMWs (r7), no extra detect hop (r9),
// no setprio on spinners (r6), no replication (r8), no poll-only spinner
// waves (r6/r12), no non-coherent speculative reads (r14), no dual-stream
// over-polling (r16), 96x256 beats all other topologies (r10/r15/r17),
// VGPR must fit weights (r4/r10), LDS stride 33 (r13), first-sweep
// delay-alignment (r18).

#define DD 768
#define NSTEPS 8192
#define NWG 96
#define NT 256
#define ROWS_PER_WG 8
#define COLS_PER_LANE 24
#define RING 16
#define LSTRIDE 33
#define LSLOT (COLS_PER_LANE * LSTRIDE)   // 792 words per history slot

#define RING_OFF 0   // RING * DD * 8B packs in d_ws

typedef __attribute__((ext_vector_type(4))) unsigned int u32x4;
typedef __attribute__((ext_vector_type(2))) unsigned int u32x2;

__device__ __forceinline__ unsigned long long ld_tag(const unsigned long long* p) {
    return __hip_atomic_load(p, __ATOMIC_RELAXED, __HIP_MEMORY_SCOPE_AGENT);
}

// One sweep: both poll loads in flight, single wait. sc0 sc1 -> coherent
// read at the device coherence point (validated r12/r13).
__device__ __forceinline__ void sweep_ld(const unsigned long long* p4,
                                         const unsigned long long* p2,
                                         u32x4* q, u32x2* r2) {
    asm volatile("global_load_dwordx4 %0, %2, off sc0 sc1\n\t"
                 "global_load_dwordx2 %1, %3, off sc0 sc1\n\t"
                 "s_waitcnt vmcnt(0)"
                 : "=&v"(*q), "=&v"(*r2)
                 : "v"(p4), "v"(p2)
                 : "memory");
}

__global__ __launch_bounds__(NT, 1)
void ndde_kernel(const float* __restrict__ x0,
                 const float* __restrict__ tau,
                 const float* __restrict__ Wx,
                 const float* __restrict__ Wy,
                 const float* __restrict__ b,
                 float* __restrict__ out,
                 unsigned long long* __restrict__ ring)
{
    // Padded transposed f32 LDS history (r13): column i at
    // hist[slot*LSLOT + (i%24)*33 + i/24]. Dot-read bank=(k+c)%32 —
    // conflict-free; broadcast writes ~6-way.
    __shared__ float hist[RING * LSLOT];          // 50.7 KB

    const int tid = threadIdx.x;
    const int g   = blockIdx.x;
    const int r   = tid >> 5;            // local row 0..7
    const int c   = tid & 31;            // lane-within-row 0..31
    const int row = g * ROWS_PER_WG + r;
    const int cb  = c * COLS_PER_LANE;

    const float dtf = tau[0] / 10.0f;

    // ---- stage weights as f32 (cvt to f64 at use, exact) ----
    float wxf[COLS_PER_LANE], wyf[COLS_PER_LANE];
    {
        const float* px = Wx + row * DD + cb;
        const float* py = Wy + row * DD + cb;
        #pragma unroll
        for (int i = 0; i < COLS_PER_LANE / 4; ++i) {
            float4 a = *(const float4*)(px + 4 * i);
            wxf[4*i+0] = a.x; wxf[4*i+1] = a.y; wxf[4*i+2] = a.z; wxf[4*i+3] = a.w;
            float4 d2 = *(const float4*)(py + 4 * i);
            wyf[4*i+0] = d2.x; wyf[4*i+1] = d2.y; wyf[4*i+2] = d2.z; wyf[4*i+3] = d2.w;
        }
    }
    #pragma unroll
    for (int i = 0; i < COLS_PER_LANE; ++i) {
        asm volatile("" : "+v"(wxf[i]));
        asm volatile("" : "+v"(wyf[i]));
    }

    const float brow = b[row];
    float xrow = x0[row];                // lane c==0 carries x_j[row]
    if (c == 0) out[row * (NSTEPS + 1) + 0] = xrow;

    for (int j = 0; j < NSTEPS; ++j) {
        // ---- delayed half: y = x_{j-10} from LDS history (frozen math) ----
        double dy0 = 0.0, dy1 = 0.0;
        if (j <= 10) {
            const float* ys = x0 + cb;
            #pragma unroll
            for (int i = 0; i < COLS_PER_LANE / 4; ++i) {
                float4 v = *(const float4*)(ys + 4 * i);
                dy0 = fma((double)wyf[4*i+0], (double)v.x, dy0);
                dy1 = fma((double)wyf[4*i+1], (double)v.y, dy1);
                dy0 = fma((double)wyf[4*i+2], (double)v.z, dy0);
                dy1 = fma((double)wyf[4*i+3], (double)v.w, dy1);
            }
        } else {
            const float* hs = hist + ((j - 10) & (RING - 1)) * LSLOT;
            #pragma unroll
            for (int k = 0; k < COLS_PER_LANE; k += 4) {
                float v0 = hs[(k+0)*LSTRIDE + c];
                float v1 = hs[(k+1)*LSTRIDE + c];
                float v2 = hs[(k+2)*LSTRIDE + c];
                float v3 = hs[(k+3)*LSTRIDE + c];
                dy0 = fma((double)wyf[k+0], (double)v0, dy0);
                dy1 = fma((double)wyf[k+1], (double)v1, dy1);
                dy0 = fma((double)wyf[k+2], (double)v2, dy0);
                dy1 = fma((double)wyf[k+3], (double)v3, dy1);
            }
        }
        double doty = dy0 + dy1;
        #pragma unroll
        for (int off = 1; off < 32; off <<= 1)
            doty += __shfl_xor(doty, off);

        // ---- ALL 4 waves: delay-aligned first sweep, then 1-RT sweeps of
        // 3 packs/thread (2 requests, one wait), broadcast to LDS ----
        if (j >= 1) {
            const unsigned tgt = (unsigned)j;
            const unsigned long long* base = ring + (j & (RING - 1)) * DD;
            const unsigned long long* p4 = base + 2 * tid;      // packs 2t,2t+1
            const unsigned long long* p2 = base + 512 + tid;    // pack 512+t
            unsigned v0, v1, v2;

            // align first sample past the slowest publish-visible time;
            // also keeps poll traffic out of the publish window (r12/r16)
            asm volatile("s_sleep 8");

            int tries = 0;
            for (;;) {
                bool ok;
                if (tries < 2048) {
                    u32x4 q; u32x2 s;
                    sweep_ld(p4, p2, &q, &s);
                    v0 = q.x; v1 = q.z; v2 = s.x;
                    ok = (q.y == tgt) & (q.w == tgt) & (s.y == tgt);
                } else {               // r11-proven fallback (no-hang)
                    unsigned long long q0 = ld_tag(p4 + 0);
                    unsigned long long q1 = ld_tag(p4 + 1);
                    unsigned long long q2 = ld_tag(p2);
                    v0 = (unsigned)q0; v1 = (unsigned)q1; v2 = (unsigned)q2;
                    ok = ((unsigned)(q0 >> 32) == tgt) &
                         ((unsigned)(q1 >> 32) == tgt) &
                         ((unsigned)(q2 >> 32) == tgt);
                }
                if (__all(ok)) break;
                ++tries;
            }
            float* hsw = hist + (j & (RING - 1)) * LSLOT;
            const int iA = 2 * tid, iB = 2 * tid + 1, iC = 512 + tid;
            hsw[(iA % 24) * LSTRIDE + (iA / 24)] = __uint_as_float(v0);
            hsw[(iB % 24) * LSTRIDE + (iB / 24)] = __uint_as_float(v1);
            hsw[(iC % 24) * LSTRIDE + (iC / 24)] = __uint_as_float(v2);
            __syncthreads();
        }

        // ---- live half: Wx · x_j from LDS (frozen math) ----
        double dx0 = 0.0, dx1 = 0.0;
        if (j == 0) {
            const float* xs = x0 + cb;
            #pragma unroll
            for (int i = 0; i < COLS_PER_LANE / 4; ++i) {
                float4 v = *(const float4*)(xs + 4 * i);
                dx0 = fma((double)wxf[4*i+0], (double)v.x, dx0);
                dx1 = fma((double)wxf[4*i+1], (double)v.y, dx1);
                dx0 = fma((double)wxf[4*i+2], (double)v.z, dx0);
                dx1 = fma((double)wxf[4*i+3], (double)v.w, dx1);
            }
        } else {
            const float* hs = hist + (j & (RING - 1)) * LSLOT;
            #pragma unroll
            for (int k = 0; k < COLS_PER_LANE; k += 4) {
                float v0 = hs[(k+0)*LSTRIDE + c];
                float v1 = hs[(k+1)*LSTRIDE + c];
                float v2 = hs[(k+2)*LSTRIDE + c];
                float v3 = hs[(k+3)*LSTRIDE + c];
                dx0 = fma((double)wxf[k+0], (double)v0, dx0);
                dx1 = fma((double)wxf[k+1], (double)v1, dx1);
                dx0 = fma((double)wxf[k+2], (double)v2, dx0);
                dx1 = fma((double)wxf[k+3], (double)v3, dx1);
            }
        }
        double dotx = dx0 + dx1;
        #pragma unroll
        for (int off = 1; off < 32; off <<= 1)
            dotx += __shfl_xor(dotx, off);

        if (c == 0) {
            // z = (dot1_f32 + dot2_f32) + b, all fp32 adds (frozen)
            float z = __fadd_rn(__fadd_rn((float)dotx, (float)doty), brow);
            float th;
            float az = fabsf(z);
            if (az < 9.3f) th = (float)tanh((double)z);  // correctly-rounded
            else           th = (z > 0.0f) ? 1.0f : -1.0f;
            // x_next = x + dt*F, fp32 mul then fp32 add (frozen)
            xrow = __fadd_rn(xrow, __fmul_rn(dtf, th));

            // publish: (value|tag) in one relaxed agent-scope 8B store
            unsigned long long pack =
                ((unsigned long long)(unsigned)(j + 1) << 32) |
                (unsigned long long)__float_as_uint(xrow);
            __hip_atomic_store(&ring[((j + 1) & (RING - 1)) * DD + row], pack,
                               __ATOMIC_RELAXED, __HIP_MEMORY_SCOPE_AGENT);

            // trajectory write — off the critical path
            out[row * (NSTEPS + 1) + (j + 1)] = xrow;
        }
    }
}

extern "C" void kernel_launch(void* const* d_in, const int* in_sizes, int n_in,
                              void* d_out, int out_size, void* d_ws, size_t ws_size,
                              hipStream_t stream) {
    (void)in_sizes; (void)n_in; (void)out_size; (void)ws_size;

    const float* x0  = (const float*)d_in[0];
    const float* tau = (const float*)d_in[1];
    const float* Wx  = (const float*)d_in[2];
    const float* Wy  = (const float*)d_in[3];
    const float* b   = (const float*)d_in[4];
    float* out = (float*)d_out;

    unsigned long long* ring = (unsigned long long*)((char*)d_ws + RING_OFF);

    // No memset needed: strict tag==j matching rejects 0xAA poison and stale
    // replay tags (slot j%16 is freshly rewritten long before step j needs it).
    ndde_kernel<<<NWG, NT, 0, stream>>>(x0, tau, Wx, Wy, b, out, ring);
}

// Round 20
// 13953.754 us; speedup vs baseline: 1.0185x; 1.0185x over previous
//
#include <hip/hip_runtime.h>
#include <math.h>

// NDDE forward-Euler DDE solve, D=768, N=8192 steps.
// x_{j+1} = x_j + dt * tanh(Wx x_j + Wy x_{j-10} + b),  dt = tau/10.
// Output: trajectory [D][N+1] fp32, out[i*(N+1)+k] = x_k[i].
//
// NUMERICS ARE FROZEN (passes at absmax 16.0 / thr 16.4): fp64-exact dots
// rounded per-dot to fp32; fp32 adds for z; correctly-rounded fp32 tanh via
// fp64; fp32 state update mul-then-add; per-row 32-lane x 24-col ownership,
// FMA order and shuffle reduction tree IDENTICAL to rounds 5/11/13/18.
//
// Round 20 = r18 (13.79 ms best; s_sleep 5 first-sweep alignment — r19
// proved sleep 8 oversleeps) + ONE change: minimum-request sweeps.
// 192 pollers x 2 global_load_dwordx4 (second via offset:16, same address,
// back-to-back issue, ONE waitcnt = still 1 RT) cover all 768 packs with
// 384 requests/WG instead of 512 (threads' x4+x2 pairs). Device sweep
// requests drop 25% (49k->37k per round) — attacking the MALL queueing
// term r16 proved live. Wave 3 skips polling and parks on the barrier
// (early ARRIVAL, not spinning — r12's poison was in-window spinning).
//
// Encoded lessons: no fences (r3), no RMWs (r7), no extra detect hop (r9),
// no setprio on spinners (r6), no replication (r8), no poll-only spinner
// waves (r6/r12), no non-coherent speculative reads (r14), no dual-stream
// over-polling (r16), 96x256 beats all other topologies (r10/r15/r17),
// VGPR must fit weights (r4/r10), LDS stride 33 (r13), first-sweep
// delay-alignment at s_sleep 5 (r18/r19).

#define DD 768
#define NSTEPS 8192
#define NWG 96
#define NT 256
#define ROWS_PER_WG 8
#define COLS_PER_LANE 24
#define RING 16
#define LSTRIDE 33
#define LSLOT (COLS_PER_LANE * LSTRIDE)   // 792 words per history slot

#define RING_OFF 0   // RING * DD * 8B packs in d_ws

typedef __attribute__((ext_vector_type(4))) unsigned int u32x4;

__device__ __forceinline__ unsigned long long ld_tag(const unsigned long long* p) {
    return __hip_atomic_load(p, __ATOMIC_RELAXED, __HIP_MEMORY_SCOPE_AGENT);
}

// One sweep: 4 packs (32B) via two back-to-back dwordx4 (second at
// offset:16), single wait -> one RT. sc0 sc1 = device-coherent read
// (validated r12/r13/r18).
__device__ __forceinline__ void sweep_ld4(const unsigned long long* p,
                                          u32x4* q0, u32x4* q1) {
    asm volatile("global_load_dwordx4 %0, %2, off sc0 sc1\n\t"
                 "global_load_dwordx4 %1, %2, off offset:16 sc0 sc1\n\t"
                 "s_waitcnt vmcnt(0)"
                 : "=&v"(*q0), "=&v"(*q1)
                 : "v"(p)
                 : "memory");
}

__global__ __launch_bounds__(NT, 1)
void ndde_kernel(const float* __restrict__ x0,
                 const float* __restrict__ tau,
                 const float* __restrict__ Wx,
                 const float* __restrict__ Wy,
                 const float* __restrict__ b,
                 float* __restrict__ out,
                 unsigned long long* __restrict__ ring)
{
    // Padded transposed f32 LDS history (r13): column i at
    // hist[slot*LSLOT + (i%24)*33 + i/24]. Dot-read bank=(k+c)%32 —
    // conflict-free; broadcast writes ~6-way.
    __shared__ float hist[RING * LSLOT];          // 50.7 KB

    const int tid = threadIdx.x;
    const int g   = blockIdx.x;
    const int r   = tid >> 5;            // local row 0..7
    const int c   = tid & 31;            // lane-within-row 0..31
    const int row = g * ROWS_PER_WG + r;
    const int cb  = c * COLS_PER_LANE;

    const float dtf = tau[0] / 10.0f;

    // ---- stage weights as f32 (cvt to f64 at use, exact) ----
    float wxf[COLS_PER_LANE], wyf[COLS_PER_LANE];
    {
        const float* px = Wx + row * DD + cb;
        const float* py = Wy + row * DD + cb;
        #pragma unroll
        for (int i = 0; i < COLS_PER_LANE / 4; ++i) {
            float4 a = *(const float4*)(px + 4 * i);
            wxf[4*i+0] = a.x; wxf[4*i+1] = a.y; wxf[4*i+2] = a.z; wxf[4*i+3] = a.w;
            float4 d2 = *(const float4*)(py + 4 * i);
            wyf[4*i+0] = d2.x; wyf[4*i+1] = d2.y; wyf[4*i+2] = d2.z; wyf[4*i+3] = d2.w;
        }
    }
    #pragma unroll
    for (int i = 0; i < COLS_PER_LANE; ++i) {
        asm volatile("" : "+v"(wxf[i]));
        asm volatile("" : "+v"(wyf[i]));
    }

    const float brow = b[row];
    float xrow = x0[row];                // lane c==0 carries x_j[row]
    if (c == 0) out[row * (NSTEPS + 1) + 0] = xrow;

    for (int j = 0; j < NSTEPS; ++j) {
        // ---- delayed half: y = x_{j-10} from LDS history (frozen math) ----
        double dy0 = 0.0, dy1 = 0.0;
        if (j <= 10) {
            const float* ys = x0 + cb;
            #pragma unroll
            for (int i = 0; i < COLS_PER_LANE / 4; ++i) {
                float4 v = *(const float4*)(ys + 4 * i);
                dy0 = fma((double)wyf[4*i+0], (double)v.x, dy0);
                dy1 = fma((double)wyf[4*i+1], (double)v.y, dy1);
                dy0 = fma((double)wyf[4*i+2], (double)v.z, dy0);
                dy1 = fma((double)wyf[4*i+3], (double)v.w, dy1);
            }
        } else {
            const float* hs = hist + ((j - 10) & (RING - 1)) * LSLOT;
            #pragma unroll
            for (int k = 0; k < COLS_PER_LANE; k += 4) {
                float v0 = hs[(k+0)*LSTRIDE + c];
                float v1 = hs[(k+1)*LSTRIDE + c];
                float v2 = hs[(k+2)*LSTRIDE + c];
                float v3 = hs[(k+3)*LSTRIDE + c];
                dy0 = fma((double)wyf[k+0], (double)v0, dy0);
                dy1 = fma((double)wyf[k+1], (double)v1, dy1);
                dy0 = fma((double)wyf[k+2], (double)v2, dy0);
                dy1 = fma((double)wyf[k+3], (double)v3, dy1);
            }
        }
        double doty = dy0 + dy1;
        #pragma unroll
        for (int off = 1; off < 32; off <<= 1)
            doty += __shfl_xor(doty, off);

        // ---- threads 0..191 (waves 0-2): delay-aligned minimum-request
        // sweep (4 packs via 2 back-to-back dwordx4, 1 RT), broadcast to
        // LDS. Wave 3 parks on the barrier (early arrival, no spinning). ----
        if (j >= 1) {
            if (tid < 192) {
                const unsigned tgt = (unsigned)j;
                const unsigned long long* p =
                    ring + (j & (RING - 1)) * DD + 4 * tid;   // packs 4t..4t+3
                unsigned v0, v1, v2, v3;

                // align first sample past the slowest publish-visible time;
                // keeps poll traffic out of the publish window (r12/r16)
                asm volatile("s_sleep 5");

                int tries = 0;
                for (;;) {
                    bool ok;
                    if (tries < 2048) {
                        u32x4 q0, q1;
                        sweep_ld4(p, &q0, &q1);
                        v0 = q0.x; v1 = q0.z; v2 = q1.x; v3 = q1.z;
                        ok = (q0.y == tgt) & (q0.w == tgt) &
                             (q1.y == tgt) & (q1.w == tgt);
                    } else {           // proven fallback (no-hang)
                        unsigned long long a0 = ld_tag(p + 0);
                        unsigned long long a1 = ld_tag(p + 1);
                        unsigned long long a2 = ld_tag(p + 2);
                        unsigned long long a3 = ld_tag(p + 3);
                        v0 = (unsigned)a0; v1 = (unsigned)a1;
                        v2 = (unsigned)a2; v3 = (unsigned)a3;
                        ok = ((unsigned)(a0 >> 32) == tgt) &
                             ((unsigned)(a1 >> 32) == tgt) &
                             ((unsigned)(a2 >> 32) == tgt) &
                             ((unsigned)(a3 >> 32) == tgt);
                    }
                    if (__all(ok)) break;
                    ++tries;
                }
                float* hsw = hist + (j & (RING - 1)) * LSLOT;
                const int i0 = 4 * tid;
                hsw[((i0+0) % 24) * LSTRIDE + ((i0+0) / 24)] = __uint_as_float(v0);
                hsw[((i0+1) % 24) * LSTRIDE + ((i0+1) / 24)] = __uint_as_float(v1);
                hsw[((i0+2) % 24) * LSTRIDE + ((i0+2) / 24)] = __uint_as_float(v2);
                hsw[((i0+3) % 24) * LSTRIDE + ((i0+3) / 24)] = __uint_as_float(v3);
            }
            __syncthreads();
        }

        // ---- live half: Wx · x_j from LDS (frozen math) ----
        double dx0 = 0.0, dx1 = 0.0;
        if (j == 0) {
            const float* xs = x0 + cb;
            #pragma unroll
            for (int i = 0; i < COLS_PER_LANE / 4; ++i) {
                float4 v = *(const float4*)(xs + 4 * i);
                dx0 = fma((double)wxf[4*i+0], (double)v.x, dx0);
                dx1 = fma((double)wxf[4*i+1], (double)v.y, dx1);
                dx0 = fma((double)wxf[4*i+2], (double)v.z, dx0);
                dx1 = fma((double)wxf[4*i+3], (double)v.w, dx1);
            }
        } else {
            const float* hs = hist + (j & (RING - 1)) * LSLOT;
            #pragma unroll
            for (int k = 0; k < COLS_PER_LANE; k += 4) {
                float v0 = hs[(k+0)*LSTRIDE + c];
                float v1 = hs[(k+1)*LSTRIDE + c];
                float v2 = hs[(k+2)*LSTRIDE + c];
                float v3 = hs[(k+3)*LSTRIDE + c];
                dx0 = fma((double)wxf[k+0], (double)v0, dx0);
                dx1 = fma((double)wxf[k+1], (double)v1, dx1);
                dx0 = fma((double)wxf[k+2], (double)v2, dx0);
                dx1 = fma((double)wxf[k+3], (double)v3, dx1);
            }
        }
        double dotx = dx0 + dx1;
        #pragma unroll
        for (int off = 1; off < 32; off <<= 1)
            dotx += __shfl_xor(dotx, off);

        if (c == 0) {
            // z = (dot1_f32 + dot2_f32) + b, all fp32 adds (frozen)
            float z = __fadd_rn(__fadd_rn((float)dotx, (float)doty), brow);
            float th;
            float az = fabsf(z);
            if (az < 9.3f) th = (float)tanh((double)z);  // correctly-rounded
            else           th = (z > 0.0f) ? 1.0f : -1.0f;
            // x_next = x + dt*F, fp32 mul then fp32 add (frozen)
            xrow = __fadd_rn(xrow, __fmul_rn(dtf, th));

            // publish: (value|tag) in one relaxed agent-scope 8B store
            unsigned long long pack =
                ((unsigned long long)(unsigned)(j + 1) << 32) |
                (unsigned long long)__float_as_uint(xrow);
            __hip_atomic_store(&ring[((j + 1) & (RING - 1)) * DD + row], pack,
                               __ATOMIC_RELAXED, __HIP_MEMORY_SCOPE_AGENT);

            // trajectory write — off the critical path
            out[row * (NSTEPS + 1) + (j + 1)] = xrow;
        }
    }
}

extern "C" void kernel_launch(void* const* d_in, const int* in_sizes, int n_in,
                              void* d_out, int out_size, void* d_ws, size_t ws_size,
                              hipStream_t stream) {
    (void)in_sizes; (void)n_in; (void)out_size; (void)ws_size;

    const float* x0  = (const float*)d_in[0];
    const float* tau = (const float*)d_in[1];
    const float* Wx  = (const float*)d_in[2];
    const float* Wy  = (const float*)d_in[3];
    const float* b   = (const float*)d_in[4];
    float* out = (float*)d_out;

    unsigned long long* ring = (unsigned long long*)((char*)d_ws + RING_OFF);

    // No memset needed: strict tag==j matching rejects 0xAA poison and stale
    // replay tags (slot j%16 is freshly rewritten long before step j needs it).
    ndde_kernel<<<NWG, NT, 0, stream>>>(x0, tau, Wx, Wy, b, out, ring);
}

// Round 21
// 13781.241 us; speedup vs baseline: 1.0312x; 1.0125x over previous
//
#include <hip/hip_runtime.h>
#include <math.h>

// NDDE forward-Euler DDE solve, D=768, N=8192 steps.
// x_{j+1} = x_j + dt * tanh(Wx x_j + Wy x_{j-10} + b),  dt = tau/10.
// Output: trajectory [D][N+1] fp32, out[i*(N+1)+k] = x_k[i].
//
// FINAL (restored round-18 optimum, 13.79 ms; r19/r20 bracketing probes
// both regressed). NUMERICS FROZEN (absmax 16.0 / thr 16.4): fp64-exact
// dots rounded per-dot to fp32; fp32 adds for z; correctly-rounded fp32
// tanh via fp64; fp32 state update mul-then-add; per-row 32-lane x 24-col
// ownership, FMA order and shuffle reduction tree fixed since round 5.
//
// Structure: 96 WGs x 256 thr (4 waves, all compute+poll). Single-hop
// tagged-data protocol: producers store (value|tag) 8B packs relaxed
// agent-scope; consumers sweep 3 packs/thread via dwordx4+dwordx2 sc0 sc1
// (2 requests, ONE waitcnt = 1 RT), first sweep delay-aligned by s_sleep 5
// past the slowest publish-visible time. Transposed stride-33 f32 LDS
// history serves both x (slot j) and y (slot j-10). No fences, no RMWs,
// no spinner waves, no memset needed.
//
// Axis closure (20 rounds): protocol {fences r3, 2-hop r9, RMW r7,
// replication r8} -> single-hop wins; topology {24x1024 r10, 48x512 r17,
// 64x384 r15, 96x256} -> 96x256; sweep {12 r5, 3 r11/r13, 2 r12, 4 r20
// packs} -> 3; rate {dual-stream r16, spinners r6/r12} -> window-confined
// only; align {0, 320cy r18, 512cy r19} -> 320cy; LDS stride 33 (r13).
// Residual 4040 cy/step = agent-RT chain + 96-WG straggler spread =
// sync-latency floor (HBM 0.3%, VALU 6.3%, MFMA 0).

#define DD 768
#define NSTEPS 8192
#define NWG 96
#define NT 256
#define ROWS_PER_WG 8
#define COLS_PER_LANE 24
#define RING 16
#define LSTRIDE 33
#define LSLOT (COLS_PER_LANE * LSTRIDE)   // 792 words per history slot

#define RING_OFF 0   // RING * DD * 8B packs in d_ws

typedef __attribute__((ext_vector_type(4))) unsigned int u32x4;
typedef __attribute__((ext_vector_type(2))) unsigned int u32x2;

__device__ __forceinline__ unsigned long long ld_tag(const unsigned long long* p) {
    return __hip_atomic_load(p, __ATOMIC_RELAXED, __HIP_MEMORY_SCOPE_AGENT);
}

// One sweep: both poll loads in flight, single wait. sc0 sc1 -> coherent
// read at the device coherence point (validated r12/r13).
__device__ __forceinline__ void sweep_ld(const unsigned long long* p4,
                                         const unsigned long long* p2,
                                         u32x4* q, u32x2* r2) {
    asm volatile("global_load_dwordx4 %0, %2, off sc0 sc1\n\t"
                 "global_load_dwordx2 %1, %3, off sc0 sc1\n\t"
                 "s_waitcnt vmcnt(0)"
                 : "=&v"(*q), "=&v"(*r2)
                 : "v"(p4), "v"(p2)
                 : "memory");
}

__global__ __launch_bounds__(NT, 1)
void ndde_kernel(const float* __restrict__ x0,
                 const float* __restrict__ tau,
                 const float* __restrict__ Wx,
                 const float* __restrict__ Wy,
                 const float* __restrict__ b,
                 float* __restrict__ out,
                 unsigned long long* __restrict__ ring)
{
    // Padded transposed f32 LDS history (r13): column i at
    // hist[slot*LSLOT + (i%24)*33 + i/24]. Dot-read bank=(k+c)%32 —
    // conflict-free; broadcast writes ~6-way.
    __shared__ float hist[RING * LSLOT];          // 50.7 KB

    const int tid = threadIdx.x;
    const int g   = blockIdx.x;
    const int r   = tid >> 5;            // local row 0..7
    const int c   = tid & 31;            // lane-within-row 0..31
    const int row = g * ROWS_PER_WG + r;
    const int cb  = c * COLS_PER_LANE;

    const float dtf = tau[0] / 10.0f;

    // ---- stage weights as f32 (cvt to f64 at use, exact) ----
    float wxf[COLS_PER_LANE], wyf[COLS_PER_LANE];
    {
        const float* px = Wx + row * DD + cb;
        const float* py = Wy + row * DD + cb;
        #pragma unroll
        for (int i = 0; i < COLS_PER_LANE / 4; ++i) {
            float4 a = *(const float4*)(px + 4 * i);
            wxf[4*i+0] = a.x; wxf[4*i+1] = a.y; wxf[4*i+2] = a.z; wxf[4*i+3] = a.w;
            float4 d2 = *(const float4*)(py + 4 * i);
            wyf[4*i+0] = d2.x; wyf[4*i+1] = d2.y; wyf[4*i+2] = d2.z; wyf[4*i+3] = d2.w;
        }
    }
    #pragma unroll
    for (int i = 0; i < COLS_PER_LANE; ++i) {
        asm volatile("" : "+v"(wxf[i]));
        asm volatile("" : "+v"(wyf[i]));
    }

    const float brow = b[row];
    float xrow = x0[row];                // lane c==0 carries x_j[row]
    if (c == 0) out[row * (NSTEPS + 1) + 0] = xrow;

    for (int j = 0; j < NSTEPS; ++j) {
        // ---- delayed half: y = x_{j-10} from LDS history (frozen math) ----
        double dy0 = 0.0, dy1 = 0.0;
        if (j <= 10) {
            const float* ys = x0 + cb;
            #pragma unroll
            for (int i = 0; i < COLS_PER_LANE / 4; ++i) {
                float4 v = *(const float4*)(ys + 4 * i);
                dy0 = fma((double)wyf[4*i+0], (double)v.x, dy0);
                dy1 = fma((double)wyf[4*i+1], (double)v.y, dy1);
                dy0 = fma((double)wyf[4*i+2], (double)v.z, dy0);
                dy1 = fma((double)wyf[4*i+3], (double)v.w, dy1);
            }
        } else {
            const float* hs = hist + ((j - 10) & (RING - 1)) * LSLOT;
            #pragma unroll
            for (int k = 0; k < COLS_PER_LANE; k += 4) {
                float v0 = hs[(k+0)*LSTRIDE + c];
                float v1 = hs[(k+1)*LSTRIDE + c];
                float v2 = hs[(k+2)*LSTRIDE + c];
                float v3 = hs[(k+3)*LSTRIDE + c];
                dy0 = fma((double)wyf[k+0], (double)v0, dy0);
                dy1 = fma((double)wyf[k+1], (double)v1, dy1);
                dy0 = fma((double)wyf[k+2], (double)v2, dy0);
                dy1 = fma((double)wyf[k+3], (double)v3, dy1);
            }
        }
        double doty = dy0 + dy1;
        #pragma unroll
        for (int off = 1; off < 32; off <<= 1)
            doty += __shfl_xor(doty, off);

        // ---- ALL 4 waves: delay-aligned first sweep, then 1-RT sweeps of
        // 3 packs/thread (2 requests, one wait), broadcast to LDS ----
        if (j >= 1) {
            const unsigned tgt = (unsigned)j;
            const unsigned long long* base = ring + (j & (RING - 1)) * DD;
            const unsigned long long* p4 = base + 2 * tid;      // packs 2t,2t+1
            const unsigned long long* p2 = base + 512 + tid;    // pack 512+t
            unsigned v0, v1, v2;

            // align first sample past the slowest publish-visible time;
            // also keeps poll traffic out of the publish window (r12/r16)
            asm volatile("s_sleep 5");

            int tries = 0;
            for (;;) {
                bool ok;
                if (tries < 2048) {
                    u32x4 q; u32x2 s;
                    sweep_ld(p4, p2, &q, &s);
                    v0 = q.x; v1 = q.z; v2 = s.x;
                    ok = (q.y == tgt) & (q.w == tgt) & (s.y == tgt);
                } else {               // r11-proven fallback (no-hang)
                    unsigned long long q0 = ld_tag(p4 + 0);
                    unsigned long long q1 = ld_tag(p4 + 1);
                    unsigned long long q2 = ld_tag(p2);
                    v0 = (unsigned)q0; v1 = (unsigned)q1; v2 = (unsigned)q2;
                    ok = ((unsigned)(q0 >> 32) == tgt) &
                         ((unsigned)(q1 >> 32) == tgt) &
                         ((unsigned)(q2 >> 32) == tgt);
                }
                if (__all(ok)) break;
                ++tries;
            }
            float* hsw = hist + (j & (RING - 1)) * LSLOT;
            const int iA = 2 * tid, iB = 2 * tid + 1, iC = 512 + tid;
            hsw[(iA % 24) * LSTRIDE + (iA / 24)] = __uint_as_float(v0);
            hsw[(iB % 24) * LSTRIDE + (iB / 24)] = __uint_as_float(v1);
            hsw[(iC % 24) * LSTRIDE + (iC / 24)] = __uint_as_float(v2);
            __syncthreads();
        }

        // ---- live half: Wx · x_j from LDS (frozen math) ----
        double dx0 = 0.0, dx1 = 0.0;
        if (j == 0) {
            const float* xs = x0 + cb;
            #pragma unroll
            for (int i = 0; i < COLS_PER_LANE / 4; ++i) {
                float4 v = *(const float4*)(xs + 4 * i);
                dx0 = fma((double)wxf[4*i+0], (double)v.x, dx0);
                dx1 = fma((double)wxf[4*i+1], (double)v.y, dx1);
                dx0 = fma((double)wxf[4*i+2], (double)v.z, dx0);
                dx1 = fma((double)wxf[4*i+3], (double)v.w, dx1);
            }
        } else {
            const float* hs = hist + (j & (RING - 1)) * LSLOT;
            #pragma unroll
            for (int k = 0; k < COLS_PER_LANE; k += 4) {
                float v0 = hs[(k+0)*LSTRIDE + c];
                float v1 = hs[(k+1)*LSTRIDE + c];
                float v2 = hs[(k+2)*LSTRIDE + c];
                float v3 = hs[(k+3)*LSTRIDE + c];
                dx0 = fma((double)wxf[k+0], (double)v0, dx0);
                dx1 = fma((double)wxf[k+1], (double)v1, dx1);
                dx0 = fma((double)wxf[k+2], (double)v2, dx0);
                dx1 = fma((double)wxf[k+3], (double)v3, dx1);
            }
        }
        double dotx = dx0 + dx1;
        #pragma unroll
        for (int off = 1; off < 32; off <<= 1)
            dotx += __shfl_xor(dotx, off);

        if (c == 0) {
            // z = (dot1_f32 + dot2_f32) + b, all fp32 adds (frozen)
            float z = __fadd_rn(__fadd_rn((float)dotx, (float)doty), brow);
            float th;
            float az = fabsf(z);
            if (az < 9.3f) th = (float)tanh((double)z);  // correctly-rounded
            else           th = (z > 0.0f) ? 1.0f : -1.0f;
            // x_next = x + dt*F, fp32 mul then fp32 add (frozen)
            xrow = __fadd_rn(xrow, __fmul_rn(dtf, th));

            // publish: (value|tag) in one relaxed agent-scope 8B store
            unsigned long long pack =
                ((unsigned long long)(unsigned)(j + 1) << 32) |
                (unsigned long long)__float_as_uint(xrow);
            __hip_atomic_store(&ring[((j + 1) & (RING - 1)) * DD + row], pack,
                               __ATOMIC_RELAXED, __HIP_MEMORY_SCOPE_AGENT);

            // trajectory write — off the critical path
            out[row * (NSTEPS + 1) + (j + 1)] = xrow;
        }
    }
}

extern "C" void kernel_launch(void* const* d_in, const int* in_sizes, int n_in,
                              void* d_out, int out_size, void* d_ws, size_t ws_size,
                              hipStream_t stream) {
    (void)in_sizes; (void)n_in; (void)out_size; (void)ws_size;

    const float* x0  = (const float*)d_in[0];
    const float* tau = (const float*)d_in[1];
    const float* Wx  = (const float*)d_in[2];
    const float* Wy  = (const float*)d_in[3];
    const float* b   = (const float*)d_in[4];
    float* out = (float*)d_out;

    unsigned long long* ring = (unsigned long long*)((char*)d_ws + RING_OFF);

    // No memset needed: strict tag==j matching rejects 0xAA poison and stale
    // replay tags (slot j%16 is freshly rewritten long before step j needs it).
    ndde_kernel<<<NWG, NT, 0, stream>>>(x0, tau, Wx, Wy, b, out, ring);
}